// Round 1
// baseline (4816.086 us; speedup 1.0000x reference)
//
#include <hip/hip_runtime.h>
#include <math.h>

// ---------------------------------------------------------------------------
// TTT block, first-order expansion in lambda = LR*2/(B*D) = 1.2207e-6.
//   H  = tanh(alpha1*x)                  [S,B,D] rows r = t*16+b
//   TV = H@Wsᵀ + noise ; P = H@Wpᵀ
//   E0 = TV@W0ᵀ - (TV - noise)           (= tv@W0ᵀ - state)
//   x1[b,t,:] = x + P@W0ᵀ - lam*(mask∘(P@TVᵀ))@E0,  mask: src tblock <= dst tblock
//   out = gelu(H2@Wp1ᵀ)*(H2@Wp2ᵀ) + x1,  H2 = tanh(alpha2*x1)
// Second-order terms are O(lam^2 * n * |K|) ~ 3e-5 << 0.111 threshold.
// ---------------------------------------------------------------------------

typedef __bf16 bf16;
typedef __attribute__((ext_vector_type(8))) __bf16 bf16x8;
typedef __attribute__((ext_vector_type(4))) __bf16 bf16x4;
typedef __attribute__((ext_vector_type(4))) float f32x4;

#define LAM 1.220703125e-6f  // LR * 2 / (B*D)

enum { M_TV = 0, M_P = 1, M_E0 = 2, M_KP = 3, M_OUT = 4, M_V = 5, M_U = 6 };

struct GA {
  const bf16* A;  int lda;
  const bf16* B;  int ldb;
  const bf16* A2; int lda2;
  const bf16* B2; int ldb2;
  int K;
  int rowoff;
  const float* noise;
  const float* xin;
  const bf16* TVb;
  const bf16* Vb;
  float* outf;
  bf16* Cb; int ldc;
};

// One BK=32 step: stage 128x32 A/B tiles to LDS, 16 MFMAs per wave.
__device__ __forceinline__ void kstep(const bf16* __restrict__ Ap, int lda,
                                      const bf16* __restrict__ Bp, int ldb,
                                      int k0, bf16* As, bf16* Bs, int tid,
                                      int wr, int wc, int m, int ko,
                                      f32x4 acc[4][4]) {
  __syncthreads();
#pragma unroll
  for (int i = 0; i < 2; ++i) {
    int idx = tid + (i << 8);
    int row = idx >> 2;
    int k8 = (idx & 3) << 3;
    *(bf16x8*)(As + row * 32 + k8) =
        *(const bf16x8*)(Ap + (size_t)row * lda + k0 + k8);
    *(bf16x8*)(Bs + row * 32 + k8) =
        *(const bf16x8*)(Bp + (size_t)row * ldb + k0 + k8);
  }
  __syncthreads();
  bf16x8 af[4], bfr[4];
#pragma unroll
  for (int i = 0; i < 4; ++i)
    af[i] = *(const bf16x8*)(As + (wr + i * 16 + m) * 32 + ko * 8);
#pragma unroll
  for (int j = 0; j < 4; ++j)
    bfr[j] = *(const bf16x8*)(Bs + (wc + j * 16 + m) * 32 + ko * 8);
#pragma unroll
  for (int i = 0; i < 4; ++i) {
#pragma unroll
    for (int j = 0; j < 4; ++j)
      acc[i][j] =
          __builtin_amdgcn_mfma_f32_16x16x32_bf16(af[i], bfr[j], acc[i][j], 0, 0, 0);
  }
}

// NT GEMM: C[r,c] = sum_k A[r,k]*B[c,k]; 128x128 tile, 256 threads (4 waves).
template <int MODE>
__global__ __launch_bounds__(256) void gemm_nt(GA g) {
  __shared__ bf16 As[128 * 32];
  __shared__ bf16 Bs[128 * 32];

  const int bx = blockIdx.x, by = blockIdx.y;
  const int c0 = bx << 7;
  const int r0 = by << 7;  // local row-tile (global for TV/P/E0/V/U)
  if constexpr (MODE == M_KP) {
    if (c0 > g.rowoff + r0) return;  // strictly-above-diagonal tiles never read
  }

  const int tid = threadIdx.x;
  const int lane = tid & 63, wv = tid >> 6;
  const int wr = (wv >> 1) << 6, wc = (wv & 1) << 6;
  const int m = lane & 15, ko = lane >> 4;

  f32x4 acc[4][4];
#pragma unroll
  for (int i = 0; i < 4; ++i) {
#pragma unroll
    for (int j = 0; j < 4; ++j) acc[i][j] = (f32x4){0.f, 0.f, 0.f, 0.f};
  }

  int K1 = g.K;
  if constexpr (MODE == M_OUT) K1 = g.rowoff + r0 + 128;  // triangular K limit

  const bf16* Ap = g.A + (size_t)r0 * g.lda;
  const bf16* Bp = g.B + (size_t)c0 * g.ldb;
  for (int k0 = 0; k0 < K1; k0 += 32)
    kstep(Ap, g.lda, Bp, g.ldb, k0, As, Bs, tid, wr, wc, m, ko, acc);

  if constexpr (MODE == M_OUT) {  // phase 2: + P@W0ᵀ
    const bf16* Ap2 = g.A2 + (size_t)(g.rowoff + r0) * g.lda2;
    const bf16* Bp2 = g.B2 + (size_t)c0 * g.ldb2;
    for (int k0 = 0; k0 < 1024; k0 += 32)
      kstep(Ap2, g.lda2, Bp2, g.ldb2, k0, As, Bs, tid, wr, wc, m, ko, acc);
  }

  // C/D layout (m89/m91-verified): col = lane&15, row = (lane>>4)*4 + reg
#pragma unroll
  for (int i = 0; i < 4; ++i) {
#pragma unroll
    for (int j = 0; j < 4; ++j) {
      const int gc = c0 + wc + j * 16 + m;
#pragma unroll
      for (int rg = 0; rg < 4; ++rg) {
        const int grl = r0 + wr + i * 16 + ko * 4 + rg;
        float v = acc[i][j][rg];
        if constexpr (MODE == M_TV) {
          int t = grl >> 4, b = grl & 15;
          float tv = v + g.noise[((size_t)b << 20) + ((size_t)t << 10) + gc];
          g.Cb[(size_t)grl * g.ldc + gc] = (bf16)tv;
        } else if constexpr (MODE == M_P || MODE == M_V) {
          g.Cb[(size_t)grl * g.ldc + gc] = (bf16)v;
        } else if constexpr (MODE == M_E0) {
          int t = grl >> 4, b = grl & 15;
          size_t ni = ((size_t)b << 20) + ((size_t)t << 10) + gc;
          float tvv = (float)g.TVb[(size_t)grl * 1024 + gc];
          float e0 = v - (tvv - g.noise[ni]);  // state = tv - noise
          g.Cb[(size_t)grl * g.ldc + gc] = (bf16)e0;
        } else if constexpr (MODE == M_KP) {
          int rgl = g.rowoff + grl;
          float s = ((gc >> 4) <= (rgl >> 4)) ? (-LAM * v) : 0.0f;
          g.Cb[(size_t)grl * g.ldc + gc] = (bf16)s;
        } else if constexpr (MODE == M_OUT) {
          int rgl = g.rowoff + grl;
          int t = rgl >> 4, b = rgl & 15;
          size_t oi = ((size_t)b << 20) + ((size_t)t << 10) + gc;
          g.outf[oi] = v + g.xin[oi];  // x1 = readout + x
        } else if constexpr (MODE == M_U) {
          size_t oi = (size_t)grl * 1024 + gc;
          float u = v;
          float gl = 0.5f * u * (1.0f + erff(u * 0.70710678118654752f));
          g.outf[oi] = gl * (float)g.Vb[oi] + g.outf[oi];
        }
      }
    }
  }
}

// fp32 -> bf16 of the 5 weight matrices (concatenated dst)
__global__ void ew_convert(const float* w0, const float* w1, const float* w2,
                           const float* w3, const float* w4, bf16* dst) {
  int gid = blockIdx.x * 256 + threadIdx.x;
  int i4 = gid << 2;
  int mm = i4 >> 20;
  const float* src = (mm == 0) ? w0 : (mm == 1) ? w1 : (mm == 2) ? w2
                     : (mm == 3) ? w3 : w4;
  int off = i4 & 1048575;
  float4 v = *(const float4*)(src + off);
  bf16x4 o;
  o[0] = (bf16)v.x; o[1] = (bf16)v.y; o[2] = (bf16)v.z; o[3] = (bf16)v.w;
  *(bf16x4*)(dst + i4) = o;
}

// H[(t*16+b), d] = bf16(tanh(alpha1[d] * x[b,t,d]))
__global__ void ew_h1(const float* __restrict__ x, const float* __restrict__ a1,
                      bf16* __restrict__ H) {
  int gid = blockIdx.x * 256 + threadIdx.x;
  int i4 = gid << 2;
  int d = i4 & 1023;
  int t = (i4 >> 10) & 1023;
  int b = i4 >> 20;
  float4 xv = *(const float4*)(x + i4);
  float4 av = *(const float4*)(a1 + d);
  bf16x4 o;
  o[0] = (bf16)tanhf(av.x * xv.x);
  o[1] = (bf16)tanhf(av.y * xv.y);
  o[2] = (bf16)tanhf(av.z * xv.z);
  o[3] = (bf16)tanhf(av.w * xv.w);
  *(bf16x4*)(H + (((size_t)((t << 4) + b)) << 10) + d) = o;
}

// H2[r', d] = bf16(tanh(alpha2[d] * x1[r', d])), r' flat over [B,S]
__global__ void ew_h2(const float* __restrict__ x1, const float* __restrict__ a2,
                      bf16* __restrict__ H2) {
  int gid = blockIdx.x * 256 + threadIdx.x;
  int i4 = gid << 2;
  int d = i4 & 1023;
  float4 xv = *(const float4*)(x1 + i4);
  float4 av = *(const float4*)(a2 + d);
  bf16x4 o;
  o[0] = (bf16)tanhf(av.x * xv.x);
  o[1] = (bf16)tanhf(av.y * xv.y);
  o[2] = (bf16)tanhf(av.z * xv.z);
  o[3] = (bf16)tanhf(av.w * xv.w);
  *(bf16x4*)(H2 + i4) = o;
}

// [16384 x 1024] -> [1024 x 16384] bf16 transpose, 64x64 LDS tiles
__global__ __launch_bounds__(256) void tr_e0(const bf16* __restrict__ in,
                                             bf16* __restrict__ out) {
  __shared__ bf16 tile[64][72];
  int c0 = blockIdx.x << 6;
  int r0 = blockIdx.y << 6;
  int tid = threadIdx.x;
  int lr = tid >> 4;
  int lc = (tid & 15) << 2;
#pragma unroll
  for (int ph = 0; ph < 4; ++ph) {
    int row = lr + (ph << 4);
    bf16x4 v = *(const bf16x4*)(in + (size_t)(r0 + row) * 1024 + c0 + lc);
    *(bf16x4*)(&tile[row][lc]) = v;
  }
  __syncthreads();
#pragma unroll
  for (int ph = 0; ph < 4; ++ph) {
    int oc = lr + (ph << 4);
    bf16x4 v;
    v[0] = tile[lc + 0][oc];
    v[1] = tile[lc + 1][oc];
    v[2] = tile[lc + 2][oc];
    v[3] = tile[lc + 3][oc];
    *(bf16x4*)(out + (size_t)(c0 + oc) * 16384 + r0 + lc) = v;
  }
}

extern "C" void kernel_launch(void* const* d_in, const int* in_sizes, int n_in,
                              void* d_out, int out_size, void* d_ws,
                              size_t ws_size, hipStream_t stream) {
  (void)in_sizes; (void)n_in; (void)out_size;
  const float* x = (const float*)d_in[0];
  const float* noise = (const float*)d_in[1];
  const float* a1 = (const float*)d_in[2];
  const float* a2 = (const float*)d_in[3];
  const float* Wmap = (const float*)d_in[4];
  const float* Wst = (const float*)d_in[5];
  const float* Wpr = (const float*)d_in[6];
  const float* Wp1 = (const float*)d_in[7];
  const float* Wp2 = (const float*)d_in[8];
  float* out = (float*)d_out;

  const size_t MB32 = (size_t)16384 * 1024 * 2;  // 32 MiB
  const size_t NEED = 5 * MB32 + 5 * (size_t)1048576 * 2;
  if (ws_size < NEED) return;  // insufficient scratch; fail loudly

  char* ws = (char*)d_ws;
  bf16* bufA = (bf16*)(ws);              // H -> E0 -> H2
  bf16* bufB = (bf16*)(ws + MB32);       // E0T -> Vb
  bf16* TVb = (bf16*)(ws + 2 * MB32);
  bf16* Pb = (bf16*)(ws + 3 * MB32);
  bf16* Kp = (bf16*)(ws + 4 * MB32);     // [1024 x 16384] row-panel, reused per rb
  bf16* Wcat = (bf16*)(ws + 5 * MB32);
  bf16* Wb0 = Wcat;
  bf16* Wsb = Wcat + (1 << 20);
  bf16* Wpb = Wcat + 2 * (1 << 20);
  bf16* W1b = Wcat + 3 * (1 << 20);
  bf16* W2b = Wcat + 4 * (1 << 20);

  ew_convert<<<5120, 256, 0, stream>>>(Wmap, Wst, Wpr, Wp1, Wp2, Wcat);
  ew_h1<<<16384, 256, 0, stream>>>(x, a1, bufA);

  {  // TV = H@Wsᵀ + noise
    GA g{};
    g.A = bufA; g.lda = 1024; g.B = Wsb; g.ldb = 1024; g.K = 1024;
    g.noise = noise; g.Cb = TVb; g.ldc = 1024;
    gemm_nt<M_TV><<<dim3(8, 128), 256, 0, stream>>>(g);
  }
  {  // P = H@Wpᵀ
    GA g{};
    g.A = bufA; g.lda = 1024; g.B = Wpb; g.ldb = 1024; g.K = 1024;
    g.Cb = Pb; g.ldc = 1024;
    gemm_nt<M_P><<<dim3(8, 128), 256, 0, stream>>>(g);
  }
  {  // E0 = TV@W0ᵀ - (TV - noise)   (overwrites H in bufA)
    GA g{};
    g.A = TVb; g.lda = 1024; g.B = Wb0; g.ldb = 1024; g.K = 1024;
    g.noise = noise; g.TVb = TVb; g.Cb = bufA; g.ldc = 1024;
    gemm_nt<M_E0><<<dim3(8, 128), 256, 0, stream>>>(g);
  }
  tr_e0<<<dim3(16, 256), 256, 0, stream>>>(bufA, bufB);  // E0T

  for (int rb = 0; rb < 16; ++rb) {
    {  // Kp panel: -lam * mask ∘ (P_rb @ TVᵀ)
      GA g{};
      g.A = Pb + (size_t)rb * 1024 * 1024; g.lda = 1024;
      g.B = TVb; g.ldb = 1024; g.K = 1024;
      g.rowoff = rb * 1024; g.Cb = Kp; g.ldc = 16384;
      gemm_nt<M_KP><<<dim3((rb + 1) * 8, 8), 256, 0, stream>>>(g);
    }
    {  // x1 rows: Kp@E0Tᵀ (triangular K) + P@W0ᵀ + x  -> d_out
      GA g{};
      g.A = Kp; g.lda = 16384;
      g.B = bufB; g.ldb = 16384;
      g.A2 = Pb; g.lda2 = 1024;
      g.B2 = Wb0; g.ldb2 = 1024;
      g.rowoff = rb * 1024;
      g.xin = x; g.outf = out;
      gemm_nt<M_OUT><<<dim3(8, 8), 256, 0, stream>>>(g);
    }
  }

  ew_h2<<<16384, 256, 0, stream>>>(out, a2, bufA);  // H2 (bufA free)
  {  // V = H2@Wp2ᵀ (bufB free after panels)
    GA g{};
    g.A = bufA; g.lda = 1024; g.B = W2b; g.ldb = 1024; g.K = 1024;
    g.Cb = bufB; g.ldc = 1024;
    gemm_nt<M_V><<<dim3(8, 128), 256, 0, stream>>>(g);
  }
  {  // out = gelu(H2@Wp1ᵀ)*V + x1
    GA g{};
    g.A = bufA; g.lda = 1024; g.B = W1b; g.ldb = 1024; g.K = 1024;
    g.Vb = bufB; g.outf = out;
    gemm_nt<M_U><<<dim3(8, 128), 256, 0, stream>>>(g);
  }
}

// Round 2
// 1005.652 us; speedup vs baseline: 4.7890x; 4.7890x over previous
//
#include <hip/hip_runtime.h>
#include <math.h>

// ---------------------------------------------------------------------------
// TTT block, first-order expansion in lambda = LR*2/(B*D) = 1.2207e-6,
// chunked linear-attention form (chunk = 64 timesteps = 1024 rows):
//   H  = tanh(alpha1*x)                  rows r = t*16+b
//   TV = H@Wsᵀ + noise ; P = H@Wpᵀ ; E0 = TV@W0ᵀ - (TV - noise)
//   Cᵀ_j = E0ᵀ_j TV_j ; Sᵀ_i = -lam * Σ_{j<i} Cᵀ_j   (exclusive prefix, D×D)
//   x1_i = x + P_i@W0ᵀ + P_i@(Sᵀ_i)ᵀ-form + Kp_i@E0_i,
//     Kp_i = -lam * mask16∘(P_i TV_iᵀ)  (triangular within chunk)
//   out = gelu(H2@Wp1ᵀ)*(H2@Wp2ᵀ) + x1,  H2 = tanh(alpha2*x1)
// ---------------------------------------------------------------------------

typedef __bf16 bf16;
typedef __attribute__((ext_vector_type(8))) __bf16 bf16x8;
typedef __attribute__((ext_vector_type(4))) __bf16 bf16x4;
typedef __attribute__((ext_vector_type(4))) float f32x4;

#define LAM 1.220703125e-6f  // LR * 2 / (B*D)

enum { M_TV = 0, M_P = 1, M_E0 = 2, M_CT = 3, M_KP = 4, M_OUT = 5, M_U = 6 };

struct GA {
  const bf16* A;  int lda;   // phase-1 operands
  const bf16* B;  int ldb;
  const bf16* A2; int lda2;  // phase-2 A (M_OUT: P)
  const bf16* B2; int ldb2;  // phase-2 B (M_OUT: S^T)
  const bf16* B3; int ldb3;  // phase-3 B (M_OUT: W0)
  int K;
  const float* noise;
  const float* xin;
  const bf16* TVb;
  const bf16* Vb;
  float* outf;
  bf16* Cb; int ldc;
};

// One BK=32 step: stage 128x32 A/B tiles to LDS, 16 MFMAs per wave.
__device__ __forceinline__ void kstep(const bf16* __restrict__ Ap, int lda,
                                      const bf16* __restrict__ Bp, int ldb,
                                      int k0, bf16* As, bf16* Bs, int tid,
                                      int wr, int wc, int m, int ko,
                                      f32x4 acc[4][4]) {
  __syncthreads();
#pragma unroll
  for (int i = 0; i < 2; ++i) {
    int idx = tid + (i << 8);
    int row = idx >> 2;
    int k8 = (idx & 3) << 3;
    *(bf16x8*)(As + row * 32 + k8) =
        *(const bf16x8*)(Ap + (size_t)row * lda + k0 + k8);
    *(bf16x8*)(Bs + row * 32 + k8) =
        *(const bf16x8*)(Bp + (size_t)row * ldb + k0 + k8);
  }
  __syncthreads();
  bf16x8 af[4], bfr[4];
#pragma unroll
  for (int i = 0; i < 4; ++i)
    af[i] = *(const bf16x8*)(As + (wr + i * 16 + m) * 32 + ko * 8);
#pragma unroll
  for (int j = 0; j < 4; ++j)
    bfr[j] = *(const bf16x8*)(Bs + (wc + j * 16 + m) * 32 + ko * 8);
#pragma unroll
  for (int i = 0; i < 4; ++i) {
#pragma unroll
    for (int j = 0; j < 4; ++j)
      acc[i][j] =
          __builtin_amdgcn_mfma_f32_16x16x32_bf16(af[i], bfr[j], acc[i][j], 0, 0, 0);
  }
}

// NT GEMM: C[r,c] = sum_k A[r,k]*B[c,k]; 128x128 tile, 256 threads (4 waves).
// blockIdx.z batches chunks for M_CT / M_KP / M_OUT.
template <int MODE>
__global__ __launch_bounds__(256) void gemm_nt(GA g) {
  __shared__ bf16 As[128 * 32];
  __shared__ bf16 Bs[128 * 32];

  const int bx = blockIdx.x, by = blockIdx.y, bz = blockIdx.z;
  const int c0 = bx << 7;
  const int r0 = by << 7;  // row-tile within chunk (or global when z==1)
  if constexpr (MODE == M_KP) {
    if (c0 > r0) return;  // strictly-above-diagonal tiles never read
  }

  size_t zA = 0, zB = 0, zC = 0;
  if constexpr (MODE == M_CT) { zA = (size_t)bz << 10; zB = zA; zC = (size_t)bz << 20; }
  if constexpr (MODE == M_KP) { zA = (size_t)bz << 20; zB = zA; zC = zA; }
  if constexpr (MODE == M_OUT) { zA = (size_t)bz << 20; zB = (size_t)bz << 10; }

  const int tid = threadIdx.x;
  const int lane = tid & 63, wv = tid >> 6;
  const int wr = (wv >> 1) << 6, wc = (wv & 1) << 6;
  const int m = lane & 15, ko = lane >> 4;

  f32x4 acc[4][4];
#pragma unroll
  for (int i = 0; i < 4; ++i) {
#pragma unroll
    for (int j = 0; j < 4; ++j) acc[i][j] = (f32x4){0.f, 0.f, 0.f, 0.f};
  }

  int K1 = g.K;
  if constexpr (MODE == M_OUT) K1 = r0 + 128;  // triangular (Kp cols > r0+127 are 0)

  const bf16* Ap = g.A + zA + (size_t)r0 * g.lda;
  const bf16* Bp = g.B + zB + (size_t)c0 * g.ldb;
  for (int k0 = 0; k0 < K1; k0 += 32)
    kstep(Ap, g.lda, Bp, g.ldb, k0, As, Bs, tid, wr, wc, m, ko, acc);

  if constexpr (MODE == M_OUT) {  // phase 2: + P_i @ S^T_i ; phase 3: + P_i @ W0^T
    const bf16* Ap2 = g.A2 + zA + (size_t)r0 * g.lda2;
    const bf16* Bp2 = g.B2 + zA + (size_t)c0 * g.ldb2;  // S^T chunk bz
    for (int k0 = 0; k0 < 1024; k0 += 32)
      kstep(Ap2, g.lda2, Bp2, g.ldb2, k0, As, Bs, tid, wr, wc, m, ko, acc);
    const bf16* Bp3 = g.B3 + (size_t)c0 * g.ldb3;
    for (int k0 = 0; k0 < 1024; k0 += 32)
      kstep(Ap2, g.lda2, Bp3, g.ldb3, k0, As, Bs, tid, wr, wc, m, ko, acc);
  }

  // C/D layout (m89/m91-verified): col = lane&15, row = (lane>>4)*4 + reg
#pragma unroll
  for (int i = 0; i < 4; ++i) {
#pragma unroll
    for (int j = 0; j < 4; ++j) {
      const int gc = c0 + wc + j * 16 + m;
#pragma unroll
      for (int rg = 0; rg < 4; ++rg) {
        const int grl = r0 + wr + i * 16 + ko * 4 + rg;
        float v = acc[i][j][rg];
        if constexpr (MODE == M_TV) {
          int t = grl >> 4, b = grl & 15;
          float tv = v + g.noise[((size_t)b << 20) + ((size_t)t << 10) + gc];
          g.Cb[(size_t)grl * g.ldc + gc] = (bf16)tv;
        } else if constexpr (MODE == M_P) {
          g.Cb[(size_t)grl * g.ldc + gc] = (bf16)v;
        } else if constexpr (MODE == M_CT) {
          g.Cb[zC + (size_t)grl * g.ldc + gc] = (bf16)v;
        } else if constexpr (MODE == M_E0) {
          int t = grl >> 4, b = grl & 15;
          size_t ni = ((size_t)b << 20) + ((size_t)t << 10) + gc;
          float tvv = (float)g.TVb[(size_t)grl * 1024 + gc];
          float e0 = v - (tvv - g.noise[ni]);  // state = tv - noise
          g.Cb[(size_t)grl * g.ldc + gc] = (bf16)e0;
        } else if constexpr (MODE == M_KP) {
          float s = ((gc >> 4) <= (grl >> 4)) ? (-LAM * v) : 0.0f;
          g.Cb[zC + (size_t)grl * g.ldc + gc] = (bf16)s;
        } else if constexpr (MODE == M_OUT) {
          int rgl = (bz << 10) + grl;
          int t = rgl >> 4, b = rgl & 15;
          size_t oi = ((size_t)b << 20) + ((size_t)t << 10) + gc;
          g.outf[oi] = v + g.xin[oi];  // x1 = readout + x
        } else if constexpr (MODE == M_U) {
          size_t oi = (size_t)grl * 1024 + gc;
          float u = v;
          float gl = 0.5f * u * (1.0f + erff(u * 0.70710678118654752f));
          g.outf[oi] = gl * (float)g.Vb[oi] + g.outf[oi];
        }
      }
    }
  }
}

// fp32 -> bf16 of the 5 weight matrices (concatenated dst)
__global__ void ew_convert(const float* w0, const float* w1, const float* w2,
                           const float* w3, const float* w4, bf16* dst) {
  int gid = blockIdx.x * 256 + threadIdx.x;
  int i4 = gid << 2;
  int mm = i4 >> 20;
  const float* src = (mm == 0) ? w0 : (mm == 1) ? w1 : (mm == 2) ? w2
                     : (mm == 3) ? w3 : w4;
  int off = i4 & 1048575;
  float4 v = *(const float4*)(src + off);
  bf16x4 o;
  o[0] = (bf16)v.x; o[1] = (bf16)v.y; o[2] = (bf16)v.z; o[3] = (bf16)v.w;
  *(bf16x4*)(dst + i4) = o;
}

// H[(t*16+b), d] = bf16(tanh(alpha1[d] * x[b,t,d]))
__global__ void ew_h1(const float* __restrict__ x, const float* __restrict__ a1,
                      bf16* __restrict__ H) {
  int gid = blockIdx.x * 256 + threadIdx.x;
  int i4 = gid << 2;
  int d = i4 & 1023;
  int t = (i4 >> 10) & 1023;
  int b = i4 >> 20;
  float4 xv = *(const float4*)(x + i4);
  float4 av = *(const float4*)(a1 + d);
  bf16x4 o;
  o[0] = (bf16)tanhf(av.x * xv.x);
  o[1] = (bf16)tanhf(av.y * xv.y);
  o[2] = (bf16)tanhf(av.z * xv.z);
  o[3] = (bf16)tanhf(av.w * xv.w);
  *(bf16x4*)(H + (((size_t)((t << 4) + b)) << 10) + d) = o;
}

// H2[r', d] = bf16(tanh(alpha2[d] * x1[r', d])), r' flat over [B,S]
__global__ void ew_h2(const float* __restrict__ x1, const float* __restrict__ a2,
                      bf16* __restrict__ H2) {
  int gid = blockIdx.x * 256 + threadIdx.x;
  int i4 = gid << 2;
  int d = i4 & 1023;
  float4 xv = *(const float4*)(x1 + i4);
  float4 av = *(const float4*)(a2 + d);
  bf16x4 o;
  o[0] = (bf16)tanhf(av.x * xv.x);
  o[1] = (bf16)tanhf(av.y * xv.y);
  o[2] = (bf16)tanhf(av.z * xv.z);
  o[3] = (bf16)tanhf(av.w * xv.w);
  *(bf16x4*)(H2 + i4) = o;
}

// exclusive prefix over 16 chunk matrices, scaled by -lam; in-place safe
__global__ void prefix_s(const bf16* __restrict__ C, bf16* __restrict__ S) {
  int gid = blockIdx.x * 256 + threadIdx.x;  // 262144 threads
  size_t base = (size_t)gid << 2;
  float ac0 = 0.f, ac1 = 0.f, ac2 = 0.f, ac3 = 0.f;
#pragma unroll
  for (int j = 0; j < 16; ++j) {
    size_t off = ((size_t)j << 20) + base;
    bf16x4 c = *(const bf16x4*)(C + off);
    bf16x4 o;
    o[0] = (bf16)(-LAM * ac0);
    o[1] = (bf16)(-LAM * ac1);
    o[2] = (bf16)(-LAM * ac2);
    o[3] = (bf16)(-LAM * ac3);
    *(bf16x4*)(S + off) = o;
    ac0 += (float)c[0]; ac1 += (float)c[1];
    ac2 += (float)c[2]; ac3 += (float)c[3];
  }
}

// [16384 x 1024] -> [1024 x 16384] bf16 transpose, 64x64 LDS tiles
__global__ __launch_bounds__(256) void tr_e0(const bf16* __restrict__ in,
                                             bf16* __restrict__ out) {
  __shared__ bf16 tile[64][72];
  int c0 = blockIdx.x << 6;
  int r0 = blockIdx.y << 6;
  int tid = threadIdx.x;
  int lr = tid >> 4;
  int lc = (tid & 15) << 2;
#pragma unroll
  for (int ph = 0; ph < 4; ++ph) {
    int row = lr + (ph << 4);
    bf16x4 v = *(const bf16x4*)(in + (size_t)(r0 + row) * 1024 + c0 + lc);
    *(bf16x4*)(&tile[row][lc]) = v;
  }
  __syncthreads();
#pragma unroll
  for (int ph = 0; ph < 4; ++ph) {
    int oc = lr + (ph << 4);
    bf16x4 v;
    v[0] = tile[lc + 0][oc];
    v[1] = tile[lc + 1][oc];
    v[2] = tile[lc + 2][oc];
    v[3] = tile[lc + 3][oc];
    *(bf16x4*)(out + (size_t)(c0 + oc) * 16384 + r0 + lc) = v;
  }
}

extern "C" void kernel_launch(void* const* d_in, const int* in_sizes, int n_in,
                              void* d_out, int out_size, void* d_ws,
                              size_t ws_size, hipStream_t stream) {
  (void)in_sizes; (void)n_in; (void)out_size;
  const float* x = (const float*)d_in[0];
  const float* noise = (const float*)d_in[1];
  const float* a1 = (const float*)d_in[2];
  const float* a2 = (const float*)d_in[3];
  const float* Wmap = (const float*)d_in[4];
  const float* Wst = (const float*)d_in[5];
  const float* Wpr = (const float*)d_in[6];
  const float* Wp1 = (const float*)d_in[7];
  const float* Wp2 = (const float*)d_in[8];
  float* out = (float*)d_out;

  const size_t MB32 = (size_t)16384 * 1024 * 2;  // 32 MiB
  const size_t NEED = 5 * MB32 + 5 * (size_t)1048576 * 2;  // 170 MiB
  if (ws_size < NEED) return;  // insufficient scratch; fail loudly

  char* ws = (char*)d_ws;
  bf16* s0 = (bf16*)(ws);              // H -> E0 -> C^T -> S^T -> H2
  bf16* s1 = (bf16*)(ws + MB32);       // TV -> V
  bf16* s2 = (bf16*)(ws + 2 * MB32);   // P
  bf16* s3 = (bf16*)(ws + 3 * MB32);   // E0^T [1024 x 16384]
  bf16* s4 = (bf16*)(ws + 4 * MB32);   // TV^T -> Kp[16][1024][1024]
  bf16* Wcat = (bf16*)(ws + 5 * MB32);
  bf16* Wb0 = Wcat;
  bf16* Wsb = Wcat + (1 << 20);
  bf16* Wpb = Wcat + 2 * (1 << 20);
  bf16* W1b = Wcat + 3 * (1 << 20);
  bf16* W2b = Wcat + 4 * (1 << 20);

  ew_convert<<<5120, 256, 0, stream>>>(Wmap, Wst, Wpr, Wp1, Wp2, Wcat);
  ew_h1<<<16384, 256, 0, stream>>>(x, a1, s0);

  {  // TV = H@Wsᵀ + noise -> s1
    GA g{};
    g.A = s0; g.lda = 1024; g.B = Wsb; g.ldb = 1024; g.K = 1024;
    g.noise = noise; g.Cb = s1; g.ldc = 1024;
    gemm_nt<M_TV><<<dim3(8, 128), 256, 0, stream>>>(g);
  }
  {  // P = H@Wpᵀ -> s2
    GA g{};
    g.A = s0; g.lda = 1024; g.B = Wpb; g.ldb = 1024; g.K = 1024;
    g.Cb = s2; g.ldc = 1024;
    gemm_nt<M_P><<<dim3(8, 128), 256, 0, stream>>>(g);
  }
  {  // E0 = TV@W0ᵀ - (TV - noise) -> s0 (H dead)
    GA g{};
    g.A = s1; g.lda = 1024; g.B = Wb0; g.ldb = 1024; g.K = 1024;
    g.noise = noise; g.TVb = s1; g.Cb = s0; g.ldc = 1024;
    gemm_nt<M_E0><<<dim3(8, 128), 256, 0, stream>>>(g);
  }
  tr_e0<<<dim3(16, 256), 256, 0, stream>>>(s0, s3);  // E0^T  (s0 free)
  tr_e0<<<dim3(16, 256), 256, 0, stream>>>(s1, s4);  // TV^T

  {  // C^T_j[b,a] = sum_r E0[r,b]*TV[r,a] -> s0[j]
    GA g{};
    g.A = s3; g.lda = 16384; g.B = s4; g.ldb = 16384; g.K = 1024;
    g.Cb = s0; g.ldc = 1024;
    gemm_nt<M_CT><<<dim3(8, 8, 16), 256, 0, stream>>>(g);
  }
  prefix_s<<<1024, 256, 0, stream>>>(s0, s0);  // S^T = -lam * excl-prefix, in-place

  {  // Kp_i = -lam * mask16 ∘ (P_i @ TV_iᵀ) -> s4 (TV^T dead)
    GA g{};
    g.A = s2; g.lda = 1024; g.B = s1; g.ldb = 1024; g.K = 1024;
    g.Cb = s4; g.ldc = 1024;
    gemm_nt<M_KP><<<dim3(8, 8, 16), 256, 0, stream>>>(g);
  }
  {  // x1_i = Kp_i@E0_i (tri-K) + P_i@S^T_i + P_i@W0ᵀ + x -> d_out
    GA g{};
    g.A = s4; g.lda = 1024;        // Kp chunk
    g.B = s3; g.ldb = 16384;       // E0^T (chunk col offset via z)
    g.A2 = s2; g.lda2 = 1024;      // P chunk
    g.B2 = s0; g.ldb2 = 1024;      // S^T chunk
    g.B3 = Wb0; g.ldb3 = 1024;     // W0
    g.xin = x; g.outf = out;
    gemm_nt<M_OUT><<<dim3(8, 8, 16), 256, 0, stream>>>(g);
  }

  ew_h2<<<16384, 256, 0, stream>>>(out, a2, s0);  // H2 -> s0 (S^T dead)
  {  // V = H2@Wp2ᵀ -> s1 (TV dead)
    GA g{};
    g.A = s0; g.lda = 1024; g.B = W2b; g.ldb = 1024; g.K = 1024;
    g.Cb = s1; g.ldc = 1024;
    gemm_nt<M_P><<<dim3(8, 128), 256, 0, stream>>>(g);
  }
  {  // out = gelu(H2@Wp1ᵀ)*V + x1
    GA g{};
    g.A = s0; g.lda = 1024; g.B = W1b; g.ldb = 1024; g.K = 1024;
    g.Vb = s1; g.outf = out;
    gemm_nt<M_U><<<dim3(8, 128), 256, 0, stream>>>(g);
  }
}

// Round 3
// 982.834 us; speedup vs baseline: 4.9002x; 1.0232x over previous
//
#include <hip/hip_runtime.h>
#include <math.h>

// ---------------------------------------------------------------------------
// TTT block, first-order expansion in lambda = LR*2/(B*D) = 1.2207e-6,
// chunked linear-attention form (chunk = 64 timesteps = 1024 rows):
//   H  = tanh(alpha1*x)                  rows r = t*16+b
//   TV = H@Wsᵀ + noise ; P = H@Wpᵀ ; E0 = TV@W0ᵀ - (TV - noise)
//   Cᵀ_j = E0ᵀ_j TV_j ; S'_i = W0 - lam * Σ_{j<i} Cᵀ_j  (excl prefix, fused W0)
//   x1_i = x + P_i@S'_iᵀ-form + Kp_i@E0_i,
//     Kp_i = -lam * mask16∘(P_i TV_iᵀ)  (triangular within chunk)
//   H2 = tanh(alpha2*x1) (fused into OUT epilogue)
//   out = gelu(H2@Wp1ᵀ)*(H2@Wp2ᵀ) + x1
// ---------------------------------------------------------------------------

typedef __bf16 bf16;
typedef __attribute__((ext_vector_type(8))) __bf16 bf16x8;
typedef __attribute__((ext_vector_type(4))) __bf16 bf16x4;
typedef __attribute__((ext_vector_type(4))) float f32x4;

#define LAM 1.220703125e-6f  // LR * 2 / (B*D)

enum { M_TV = 0, M_P = 1, M_E0 = 2, M_CT = 3, M_KP = 4, M_OUT = 5, M_U = 6 };

struct GA {
  const bf16* A;  int lda;   // phase-1 operands
  const bf16* B;  int ldb;
  const bf16* A2; int lda2;  // phase-2 A (M_OUT: P)
  const bf16* B2; int ldb2;  // phase-2 B (M_OUT: S')
  int K;
  const float* noise;
  const float* xin;
  const float* alpha2;
  const bf16* TVb;
  const bf16* Vb;
  bf16* H2b;
  float* outf;
  bf16* Cb; int ldc;
};

// async 16B global->LDS (lds dest = wave-uniform base + lane*16)
#define GLOAD_LDS16(gp, lp)                                                   \
  __builtin_amdgcn_global_load_lds(                                           \
      (const __attribute__((address_space(1))) unsigned int*)(gp),            \
      (__attribute__((address_space(3))) unsigned int*)(lp), 16, 0, 0)

// One BK=32 step: stage 128x32 A/B tiles to LDS via global_load_lds,
// 16 MFMAs per wave.
__device__ __forceinline__ void kstep(const bf16* __restrict__ Ap, int lda,
                                      const bf16* __restrict__ Bp, int ldb,
                                      int k0, bf16* As, bf16* Bs, int tid,
                                      int wr, int wc, int m, int ko,
                                      f32x4 acc[4][4]) {
  const int wv = tid >> 6, lane = tid & 63;
  __syncthreads();
#pragma unroll
  for (int i = 0; i < 2; ++i) {
    int idx = (wv << 6) + lane + (i << 8);
    int row = idx >> 2;
    int k8 = (idx & 3) << 3;
    int lbase = ((wv << 6) + (i << 8)) << 3;  // wave-uniform LDS element base
    GLOAD_LDS16(Ap + (size_t)row * lda + k0 + k8, As + lbase);
    GLOAD_LDS16(Bp + (size_t)row * ldb + k0 + k8, Bs + lbase);
  }
  __syncthreads();
  bf16x8 af[4], bfr[4];
#pragma unroll
  for (int i = 0; i < 4; ++i)
    af[i] = *(const bf16x8*)(As + (wr + i * 16 + m) * 32 + ko * 8);
#pragma unroll
  for (int j = 0; j < 4; ++j)
    bfr[j] = *(const bf16x8*)(Bs + (wc + j * 16 + m) * 32 + ko * 8);
#pragma unroll
  for (int i = 0; i < 4; ++i) {
#pragma unroll
    for (int j = 0; j < 4; ++j)
      acc[i][j] =
          __builtin_amdgcn_mfma_f32_16x16x32_bf16(af[i], bfr[j], acc[i][j], 0, 0, 0);
  }
}

// NT GEMM: C[r,c] = sum_k A[r,k]*B[c,k]; 128x128 tile, 256 threads (4 waves).
// blockIdx.z batches chunks for M_CT / M_KP / M_OUT.
template <int MODE>
__global__ __launch_bounds__(256) void gemm_nt(GA g) {
  __shared__ bf16 As[128 * 32];
  __shared__ bf16 Bs[128 * 32];

  const int bx = blockIdx.x, by = blockIdx.y, bz = blockIdx.z;
  const int c0 = bx << 7;
  const int r0 = by << 7;  // row-tile within chunk (or global when z==1)
  if constexpr (MODE == M_KP) {
    if (c0 > r0) return;  // strictly-above-diagonal tiles never read
  }

  size_t zA = 0, zB = 0, zC = 0;
  if constexpr (MODE == M_CT) { zA = (size_t)bz << 10; zB = zA; zC = (size_t)bz << 20; }
  if constexpr (MODE == M_KP) { zA = (size_t)bz << 20; zB = zA; zC = zA; }
  if constexpr (MODE == M_OUT) { zA = (size_t)bz << 20; zB = (size_t)bz << 10; }

  const int tid = threadIdx.x;
  const int lane = tid & 63, wv = tid >> 6;
  const int wr = (wv >> 1) << 6, wc = (wv & 1) << 6;
  const int m = lane & 15, ko = lane >> 4;

  f32x4 acc[4][4];
#pragma unroll
  for (int i = 0; i < 4; ++i) {
#pragma unroll
    for (int j = 0; j < 4; ++j) acc[i][j] = (f32x4){0.f, 0.f, 0.f, 0.f};
  }

  int K1 = g.K;
  if constexpr (MODE == M_OUT) K1 = r0 + 128;  // triangular (Kp cols > r0+127 are 0)

  const bf16* Ap = g.A + zA + (size_t)r0 * g.lda;
  const bf16* Bp = g.B + zB + (size_t)c0 * g.ldb;
  for (int k0 = 0; k0 < K1; k0 += 32)
    kstep(Ap, g.lda, Bp, g.ldb, k0, As, Bs, tid, wr, wc, m, ko, acc);

  if constexpr (MODE == M_OUT) {  // phase 2: + P_i @ S'^T_i  (W0 folded into S')
    const bf16* Ap2 = g.A2 + zA + (size_t)r0 * g.lda2;
    const bf16* Bp2 = g.B2 + zA + (size_t)c0 * g.ldb2;  // S' chunk bz
    for (int k0 = 0; k0 < 1024; k0 += 32)
      kstep(Ap2, g.lda2, Bp2, g.ldb2, k0, As, Bs, tid, wr, wc, m, ko, acc);
  }

  // C/D layout (m89/m91-verified): col = lane&15, row = (lane>>4)*4 + reg
#pragma unroll
  for (int i = 0; i < 4; ++i) {
#pragma unroll
    for (int j = 0; j < 4; ++j) {
      const int gc = c0 + wc + j * 16 + m;
#pragma unroll
      for (int rg = 0; rg < 4; ++rg) {
        const int grl = r0 + wr + i * 16 + ko * 4 + rg;
        float v = acc[i][j][rg];
        if constexpr (MODE == M_TV) {
          int t = grl >> 4, b = grl & 15;
          float tv = v + g.noise[((size_t)b << 20) + ((size_t)t << 10) + gc];
          g.Cb[(size_t)grl * g.ldc + gc] = (bf16)tv;
        } else if constexpr (MODE == M_P) {
          g.Cb[(size_t)grl * g.ldc + gc] = (bf16)v;
        } else if constexpr (MODE == M_CT) {
          g.Cb[zC + (size_t)grl * g.ldc + gc] = (bf16)v;
        } else if constexpr (MODE == M_E0) {
          int t = grl >> 4, b = grl & 15;
          size_t ni = ((size_t)b << 20) + ((size_t)t << 10) + gc;
          float tvv = (float)g.TVb[(size_t)grl * 1024 + gc];
          float e0 = v - (tvv - g.noise[ni]);  // state = tv - noise
          g.Cb[(size_t)grl * g.ldc + gc] = (bf16)e0;
        } else if constexpr (MODE == M_KP) {
          float s = ((gc >> 4) <= (grl >> 4)) ? (-LAM * v) : 0.0f;
          g.Cb[zC + (size_t)grl * g.ldc + gc] = (bf16)s;
        } else if constexpr (MODE == M_OUT) {
          int rgl = (bz << 10) + grl;
          int t = rgl >> 4, b = rgl & 15;
          size_t oi = ((size_t)b << 20) + ((size_t)t << 10) + gc;
          float x1 = v + g.xin[oi];
          g.outf[oi] = x1;
          g.H2b[oi] = (bf16)tanhf(g.alpha2[gc] * x1);  // fused norm_2
        } else if constexpr (MODE == M_U) {
          size_t oi = (size_t)grl * 1024 + gc;
          float u = v;
          float gl = 0.5f * u * (1.0f + erff(u * 0.70710678118654752f));
          g.outf[oi] = gl * (float)g.Vb[oi] + g.outf[oi];
        }
      }
    }
  }
}

// fp32 -> bf16 of the 5 weight matrices (concatenated dst)
__global__ void ew_convert(const float* w0, const float* w1, const float* w2,
                           const float* w3, const float* w4, bf16* dst) {
  int gid = blockIdx.x * 256 + threadIdx.x;
  int i4 = gid << 2;
  int mm = i4 >> 20;
  const float* src = (mm == 0) ? w0 : (mm == 1) ? w1 : (mm == 2) ? w2
                     : (mm == 3) ? w3 : w4;
  int off = i4 & 1048575;
  float4 v = *(const float4*)(src + off);
  bf16x4 o;
  o[0] = (bf16)v.x; o[1] = (bf16)v.y; o[2] = (bf16)v.z; o[3] = (bf16)v.w;
  *(bf16x4*)(dst + i4) = o;
}

// H[(t*16+b), d] = bf16(tanh(alpha1[d] * x[b,t,d]))
__global__ void ew_h1(const float* __restrict__ x, const float* __restrict__ a1,
                      bf16* __restrict__ H) {
  int gid = blockIdx.x * 256 + threadIdx.x;
  int i4 = gid << 2;
  int d = i4 & 1023;
  int t = (i4 >> 10) & 1023;
  int b = i4 >> 20;
  float4 xv = *(const float4*)(x + i4);
  float4 av = *(const float4*)(a1 + d);
  bf16x4 o;
  o[0] = (bf16)tanhf(av.x * xv.x);
  o[1] = (bf16)tanhf(av.y * xv.y);
  o[2] = (bf16)tanhf(av.z * xv.z);
  o[3] = (bf16)tanhf(av.w * xv.w);
  *(bf16x4*)(H + (((size_t)((t << 4) + b)) << 10) + d) = o;
}

// S'[j] = W0 - lam * (exclusive prefix of C over chunks); in-place safe
__global__ void prefix_s(const bf16* __restrict__ C, bf16* __restrict__ S,
                         const bf16* __restrict__ W0) {
  int gid = blockIdx.x * 256 + threadIdx.x;  // 262144 threads
  size_t base = (size_t)gid << 2;
  bf16x4 wv = *(const bf16x4*)(W0 + base);
  float w0 = (float)wv[0], w1 = (float)wv[1], w2 = (float)wv[2],
        w3 = (float)wv[3];
  float ac0 = 0.f, ac1 = 0.f, ac2 = 0.f, ac3 = 0.f;
#pragma unroll
  for (int j = 0; j < 16; ++j) {
    size_t off = ((size_t)j << 20) + base;
    bf16x4 c = *(const bf16x4*)(C + off);
    bf16x4 o;
    o[0] = (bf16)(w0 - LAM * ac0);
    o[1] = (bf16)(w1 - LAM * ac1);
    o[2] = (bf16)(w2 - LAM * ac2);
    o[3] = (bf16)(w3 - LAM * ac3);
    *(bf16x4*)(S + off) = o;
    ac0 += (float)c[0]; ac1 += (float)c[1];
    ac2 += (float)c[2]; ac3 += (float)c[3];
  }
}

// [16384 x 1024] -> [1024 x 16384] bf16 transpose, 64x64 LDS tiles
__global__ __launch_bounds__(256) void tr_e0(const bf16* __restrict__ in,
                                             bf16* __restrict__ out) {
  __shared__ bf16 tile[64][72];
  int c0 = blockIdx.x << 6;
  int r0 = blockIdx.y << 6;
  int tid = threadIdx.x;
  int lr = tid >> 4;
  int lc = (tid & 15) << 2;
#pragma unroll
  for (int ph = 0; ph < 4; ++ph) {
    int row = lr + (ph << 4);
    bf16x4 v = *(const bf16x4*)(in + (size_t)(r0 + row) * 1024 + c0 + lc);
    *(bf16x4*)(&tile[row][lc]) = v;
  }
  __syncthreads();
#pragma unroll
  for (int ph = 0; ph < 4; ++ph) {
    int oc = lr + (ph << 4);
    bf16x4 v;
    v[0] = tile[lc + 0][oc];
    v[1] = tile[lc + 1][oc];
    v[2] = tile[lc + 2][oc];
    v[3] = tile[lc + 3][oc];
    *(bf16x4*)(out + (size_t)(c0 + oc) * 16384 + r0 + lc) = v;
  }
}

extern "C" void kernel_launch(void* const* d_in, const int* in_sizes, int n_in,
                              void* d_out, int out_size, void* d_ws,
                              size_t ws_size, hipStream_t stream) {
  (void)in_sizes; (void)n_in; (void)out_size;
  const float* x = (const float*)d_in[0];
  const float* noise = (const float*)d_in[1];
  const float* a1 = (const float*)d_in[2];
  const float* a2 = (const float*)d_in[3];
  const float* Wmap = (const float*)d_in[4];
  const float* Wst = (const float*)d_in[5];
  const float* Wpr = (const float*)d_in[6];
  const float* Wp1 = (const float*)d_in[7];
  const float* Wp2 = (const float*)d_in[8];
  float* out = (float*)d_out;

  const size_t MB32 = (size_t)16384 * 1024 * 2;  // 32 MiB
  const size_t NEED = 5 * MB32 + 5 * (size_t)1048576 * 2;  // 170 MiB
  if (ws_size < NEED) return;  // insufficient scratch; fail loudly

  char* ws = (char*)d_ws;
  bf16* s0 = (bf16*)(ws);              // H -> E0 -> C^T -> S' -> V
  bf16* s1 = (bf16*)(ws + MB32);       // TV -> H2
  bf16* s2 = (bf16*)(ws + 2 * MB32);   // P
  bf16* s3 = (bf16*)(ws + 3 * MB32);   // E0^T [1024 x 16384]
  bf16* s4 = (bf16*)(ws + 4 * MB32);   // TV^T -> Kp[16][1024][1024]
  bf16* Wcat = (bf16*)(ws + 5 * MB32);
  bf16* Wb0 = Wcat;
  bf16* Wsb = Wcat + (1 << 20);
  bf16* Wpb = Wcat + 2 * (1 << 20);
  bf16* W1b = Wcat + 3 * (1 << 20);
  bf16* W2b = Wcat + 4 * (1 << 20);

  ew_convert<<<5120, 256, 0, stream>>>(Wmap, Wst, Wpr, Wp1, Wp2, Wcat);
  ew_h1<<<16384, 256, 0, stream>>>(x, a1, s0);

  {  // TV = H@Wsᵀ + noise -> s1
    GA g{};
    g.A = s0; g.lda = 1024; g.B = Wsb; g.ldb = 1024; g.K = 1024;
    g.noise = noise; g.Cb = s1; g.ldc = 1024;
    gemm_nt<M_TV><<<dim3(8, 128), 256, 0, stream>>>(g);
  }
  {  // P = H@Wpᵀ -> s2
    GA g{};
    g.A = s0; g.lda = 1024; g.B = Wpb; g.ldb = 1024; g.K = 1024;
    g.Cb = s2; g.ldc = 1024;
    gemm_nt<M_P><<<dim3(8, 128), 256, 0, stream>>>(g);
  }
  {  // E0 = TV@W0ᵀ - (TV - noise) -> s0 (H dead)
    GA g{};
    g.A = s1; g.lda = 1024; g.B = Wb0; g.ldb = 1024; g.K = 1024;
    g.noise = noise; g.TVb = s1; g.Cb = s0; g.ldc = 1024;
    gemm_nt<M_E0><<<dim3(8, 128), 256, 0, stream>>>(g);
  }
  tr_e0<<<dim3(16, 256), 256, 0, stream>>>(s0, s3);  // E0^T  (s0 free)
  tr_e0<<<dim3(16, 256), 256, 0, stream>>>(s1, s4);  // TV^T

  {  // C^T_j[r,c] = sum_n E0[n,r]*TV[n,c] -> s0[j]
    GA g{};
    g.A = s3; g.lda = 16384; g.B = s4; g.ldb = 16384; g.K = 1024;
    g.Cb = s0; g.ldc = 1024;
    gemm_nt<M_CT><<<dim3(8, 8, 16), 256, 0, stream>>>(g);
  }
  prefix_s<<<1024, 256, 0, stream>>>(s0, s0, Wb0);  // S' = W0 - lam*prefix

  {  // Kp_i = -lam * mask16 ∘ (P_i @ TV_iᵀ) -> s4 (TV^T dead)
    GA g{};
    g.A = s2; g.lda = 1024; g.B = s1; g.ldb = 1024; g.K = 1024;
    g.Cb = s4; g.ldc = 1024;
    gemm_nt<M_KP><<<dim3(8, 8, 16), 256, 0, stream>>>(g);
  }
  {  // x1_i = Kp_i@E0_i (tri-K) + P_i@S'_i + x -> d_out ; H2 -> s1
    GA g{};
    g.A = s4; g.lda = 1024;        // Kp chunk
    g.B = s3; g.ldb = 16384;       // E0^T (chunk col offset via z)
    g.A2 = s2; g.lda2 = 1024;      // P chunk
    g.B2 = s0; g.ldb2 = 1024;      // S' chunk
    g.xin = x; g.outf = out;
    g.alpha2 = a2; g.H2b = s1;     // fused tanh(alpha2*x1) (TV dead)
    gemm_nt<M_OUT><<<dim3(8, 8, 16), 256, 0, stream>>>(g);
  }

  {  // V = H2@Wp2ᵀ -> s0 (S' dead)
    GA g{};
    g.A = s1; g.lda = 1024; g.B = W2b; g.ldb = 1024; g.K = 1024;
    g.Cb = s0; g.ldc = 1024;
    gemm_nt<M_P><<<dim3(8, 128), 256, 0, stream>>>(g);
  }
  {  // out = gelu(H2@Wp1ᵀ)*V + x1
    GA g{};
    g.A = s1; g.lda = 1024; g.B = W1b; g.ldb = 1024; g.K = 1024;
    g.Vb = s0; g.outf = out;
    gemm_nt<M_U><<<dim3(8, 128), 256, 0, stream>>>(g);
  }
}